// Round 7
// baseline (870.028 us; speedup 1.0000x reference)
//
#include <hip/hip_runtime.h>
#include <math.h>

typedef __bf16 bf16x8 __attribute__((ext_vector_type(8)));
typedef float f32x4 __attribute__((ext_vector_type(4)));

__device__ __forceinline__ unsigned short f2bf(float x) {
  unsigned int u = __builtin_bit_cast(unsigned int, x);
  unsigned int r = (u + 0x7fffu + ((u >> 16) & 1u)) >> 16;
  return (unsigned short)r;
}
__device__ __forceinline__ float bf2f(unsigned short u) {
  return __builtin_bit_cast(float, ((unsigned int)u) << 16);
}

__device__ __forceinline__ void async16(const void* g, void* l) {
  __builtin_amdgcn_global_load_lds(
      (const __attribute__((address_space(1))) void*)g,
      (__attribute__((address_space(3))) void*)l, 16, 0, 0);
}

// f32 -> bf16 (RNE), 8 elems/thread
__global__ __launch_bounds__(256) void cvt_bf16_k(const float* __restrict__ in,
                                                  unsigned short* __restrict__ out,
                                                  int n8) {
  const int i = blockIdx.x * 256 + threadIdx.x;
  if (i >= n8) return;
  const float4* p = (const float4*)in + (long)i * 2;
  const float4 v0 = p[0], v1 = p[1];
  alignas(16) unsigned short o[8] = {f2bf(v0.x), f2bf(v0.y), f2bf(v0.z), f2bf(v0.w),
                                     f2bf(v1.x), f2bf(v1.y), f2bf(v1.z), f2bf(v1.w)};
  *(uint4*)(out + (long)i * 8) = *(uint4*)o;
}

// qkv GEMM: C[m,n] = sum_k A[m,k]*B[n,k]; A bf16 [4096,2048], B f32 [6144,2048].
// n<4096 (q,k cols): write QK[m*4096+n] bf16.
// n>=4096 (v cols): write transposed VtG[b][h][d][t] bf16 (b64-packed).
__global__ __launch_bounds__(256) void gemm_qkv(
    const unsigned short* __restrict__ A, const float* __restrict__ B,
    unsigned short* __restrict__ QK, unsigned short* __restrict__ VtG, int K) {
  __shared__ unsigned short As[128 * 32];
  __shared__ float Bs[128 * 32];
  const int tid = threadIdx.x;
  const int lane = tid & 63;
  const int w = tid >> 6;
  const int wr = w >> 1, wc = w & 1;
  const int fr = lane & 15, fq = lane >> 4;
  const long m0 = (long)blockIdx.y * 128;
  const long n0 = (long)blockIdx.x * 128;
  const int srA = lane >> 2, scA = (lane & 3) * 8;
  const int srB = lane >> 3, scB = (lane & 7) * 4;
  f32x4 acc[4][4] = {};
  for (int k0 = 0; k0 < K; k0 += 32) {
    __syncthreads();
#pragma unroll
    for (int i = 0; i < 2; i++) {
      const int r = (w * 2 + i) * 16 + srA;
      async16(A + (m0 + r) * (long)K + k0 + scA, &As[(w * 2 + i) * 512]);
    }
#pragma unroll
    for (int c = 0; c < 4; c++) {
      const int rb = (w * 4 + c) * 8 + srB;
      const int kk = scB ^ ((rb & 3) * 8);
      async16(B + (n0 + rb) * (long)K + k0 + kk, &Bs[(w * 4 + c) * 256]);
    }
    __syncthreads();
    bf16x8 a[4], b[4];
#pragma unroll
    for (int i = 0; i < 4; i++)
      a[i] = *(const bf16x8*)&As[(wr * 64 + i * 16 + fr) * 32 + fq * 8];
#pragma unroll
    for (int j = 0; j < 4; j++) {
      const int rr = wc * 64 + j * 16 + fr;
      const float* bp = &Bs[rr * 32 + ((fq * 8) ^ ((rr & 3) * 8))];
      const f32x4 lo = *(const f32x4*)bp;
      const f32x4 hi = *(const f32x4*)(bp + 4);
      union { bf16x8 v; unsigned short u[8]; } t;
      t.u[0] = f2bf(lo[0]); t.u[1] = f2bf(lo[1]);
      t.u[2] = f2bf(lo[2]); t.u[3] = f2bf(lo[3]);
      t.u[4] = f2bf(hi[0]); t.u[5] = f2bf(hi[1]);
      t.u[6] = f2bf(hi[2]); t.u[7] = f2bf(hi[3]);
      b[j] = t.v;
    }
#pragma unroll
    for (int i = 0; i < 4; i++)
#pragma unroll
      for (int j = 0; j < 4; j++)
        acc[i][j] =
            __builtin_amdgcn_mfma_f32_16x16x32_bf16(a[i], b[j], acc[i][j], 0, 0, 0);
  }
  if (blockIdx.x < 32) {  // q,k columns
#pragma unroll
    for (int i = 0; i < 4; i++)
#pragma unroll
      for (int j = 0; j < 4; j++)
#pragma unroll
        for (int r = 0; r < 4; r++) {
          const long m = m0 + wr * 64 + i * 16 + fq * 4 + r;
          const long n = n0 + wc * 64 + j * 16 + fr;
          QK[m * 4096 + n] = f2bf(acc[i][j][r]);
        }
  } else {  // v columns -> VtG[((b*16+h)*128 + d)*2048 + t]
    const int hv = (int)(blockIdx.x) - 32;  // n0 = 4096 + hv*128
    const int bb = (int)(m0 >> 11);
#pragma unroll
    for (int i = 0; i < 4; i++)
#pragma unroll
      for (int j = 0; j < 4; j++) {
        const int d = wc * 64 + j * 16 + fr;
        const long t0 = (m0 & 2047) + wr * 64 + i * 16 + fq * 4;
        alignas(8) unsigned short o[4];
#pragma unroll
        for (int r = 0; r < 4; r++) o[r] = f2bf(acc[i][j][r]);
        *(ushort4*)(VtG + ((long)(bb * 16 + hv) * 128 + d) * 2048 + t0) =
            *(ushort4*)o;
      }
  }
}

// in-place on bf16 QK rows (stride 4096): RMSNorm(q,k) (g f32), RoPE(q,k)
__global__ __launch_bounds__(256) void rms_rope(unsigned short* __restrict__ QK,
                                                const float* __restrict__ g) {
  const int m = blockIdx.x;  // 0..4095
  const int t = m & 2047;
  const int tid = threadIdx.x;
  const int lane = tid & 63, w = tid >> 6;
  unsigned short* row = QK + (long)m * 4096;
  const int base = tid * 8;
  alignas(16) unsigned short qs[8], ks[8];
  *(uint4*)qs = *(const uint4*)(row + base);
  *(uint4*)ks = *(const uint4*)(row + 2048 + base);
  float qv[8], kv[8];
  float sq = 0.f, sk = 0.f;
#pragma unroll
  for (int j = 0; j < 8; j++) {
    qv[j] = bf2f(qs[j]);
    kv[j] = bf2f(ks[j]);
    sq += qv[j] * qv[j];
    sk += kv[j] * kv[j];
  }
#pragma unroll
  for (int off = 1; off < 64; off <<= 1) {
    sq += __shfl_xor(sq, off);
    sk += __shfl_xor(sk, off);
  }
  __shared__ float red[2][4];
  if (lane == 0) {
    red[0][w] = sq;
    red[1][w] = sk;
  }
  __syncthreads();
  sq = red[0][0] + red[0][1] + red[0][2] + red[0][3];
  sk = red[1][0] + red[1][1] + red[1][2] + red[1][3];
  const float rq = rsqrtf(sq * (1.f / 2048.f) + 1e-6f);
  const float rk = rsqrtf(sk * (1.f / 2048.f) + 1e-6f);
  float qn[8], kn[8];
#pragma unroll
  for (int j = 0; j < 8; j++) {
    const float gg = g[base + j];
    qn[j] = qv[j] * rq * gg;
    kn[j] = kv[j] * rk * gg;
  }
  const int d0 = base & 127;
  alignas(16) unsigned short qo[8], ko[8];
#pragma unroll
  for (int p = 0; p < 8; p += 2) {
    const int d = d0 + p;
    const int i0 = (d < 64) ? d : d - 64;
    const int i1 = (d + 1 < 64) ? d + 1 : d - 63;
    const float kf = 13.287712379549449f / 128.f;  // log2(10000)/128
    const float a0 = (float)t * exp2f(-(4.f * i0 + 1.f) * kf);
    const float a1 = (float)t * exp2f(-(4.f * i1 + 1.f) * kf);
    float c0, s0, c1, s1;
    sincosf(a0, &s0, &c0);
    sincosf(a1, &s1, &c1);
    qo[p] = f2bf(qn[p] * c0 - qn[p + 1] * s0);
    qo[p + 1] = f2bf(qn[p + 1] * c1 + qn[p] * s1);
    ko[p] = f2bf(kn[p] * c0 - kn[p + 1] * s0);
    ko[p + 1] = f2bf(kn[p + 1] * c1 + kn[p] * s1);
  }
  *(uint4*)(row + base) = *(uint4*)qo;
  *(uint4*)(row + 2048 + base) = *(uint4*)ko;
}

// Flash attention, S^T orientation, barrier-free K-loop.
// Block = (qt, b*h); wave w owns queries qbase+w*16..+15; lane's q = fr.
// S^T = K·Q^T (A=K frag from global, B=Q regs); per-lane softmax (q=fr);
// P->Pl (per-wave LDS) -> B-frag; O^T += Vt·P (A=Vt frag from global).
__global__ __launch_bounds__(256) void attn(
    const unsigned short* __restrict__ QK, const unsigned short* __restrict__ VtG,
    unsigned short* __restrict__ Y) {
  const int qt = 31 - (int)blockIdx.x;  // big blocks dispatch first
  const int bh = blockIdx.y;
  const int b = bh >> 4, h = bh & 15;
  const int tid = threadIdx.x, lane = tid & 63, w = tid >> 6;
  const int fr = lane & 15, fq = lane >> 4;
  __shared__ unsigned short Pl[4][16 * 72];  // stride 72: 16B-aligned rows
  const int qbase = qt * 64;
  const long tokbase = (long)b * 2048;
  const unsigned short* Qrow =
      QK + (tokbase + qbase + w * 16 + fr) * 4096 + h * 128 + fq * 8;
  const unsigned short* Kbase = QK + tokbase * 4096 + h * 128 + 2048 + fq * 8;
  const unsigned short* Vbase =
      VtG + (long)(b * 16 + h) * 128 * 2048 + fq * 8;
  unsigned short* pl = &Pl[w][0];
  bf16x8 bq[4];
#pragma unroll
  for (int ks = 0; ks < 4; ks++) bq[ks] = *(const bf16x8*)(Qrow + ks * 32);
  float m_i = -1e30f, l_i = 0.f;
  f32x4 accO[8] = {};
  const float scale = 0.08838834764831845f;  // 1/sqrt(128)
  for (int kt = 0; kt <= qt; kt++) {
    f32x4 accS[4] = {};
#pragma unroll
    for (int n = 0; n < 4; n++) {
      const unsigned short* kr = Kbase + (long)(kt * 64 + n * 16 + fr) * 4096;
#pragma unroll
      for (int ks = 0; ks < 4; ks++) {
        const bf16x8 ak = *(const bf16x8*)(kr + ks * 32);
        accS[n] = __builtin_amdgcn_mfma_f32_16x16x32_bf16(ak, bq[ks], accS[n], 0, 0, 0);
      }
    }
#pragma unroll
    for (int n = 0; n < 4; n++)
#pragma unroll
      for (int r = 0; r < 4; r++) accS[n][r] *= scale;
    if (kt == qt) {  // diagonal tile: mask key > q
      const int qloc = w * 16 + fr;
#pragma unroll
      for (int n = 0; n < 4; n++)
#pragma unroll
        for (int r = 0; r < 4; r++)
          if (n * 16 + fq * 4 + r > qloc) accS[n][r] = -1e30f;
    }
    // per-lane online softmax (all 16 values share q = fr)
    float tmax = accS[0][0];
#pragma unroll
    for (int n = 0; n < 4; n++)
#pragma unroll
      for (int r = 0; r < 4; r++) tmax = fmaxf(tmax, accS[n][r]);
    tmax = fmaxf(tmax, __shfl_xor(tmax, 16));
    tmax = fmaxf(tmax, __shfl_xor(tmax, 32));
    const float mnew = fmaxf(m_i, tmax);
    const float alpha = __expf(m_i - mnew);
    float lsum = 0.f;
#pragma unroll
    for (int n = 0; n < 4; n++)
#pragma unroll
      for (int r = 0; r < 4; r++) {
        const float p = __expf(accS[n][r] - mnew);
        accS[n][r] = p;
        lsum += p;
      }
    lsum += __shfl_xor(lsum, 16);
    lsum += __shfl_xor(lsum, 32);
    l_i = l_i * alpha + lsum;
    m_i = mnew;
#pragma unroll
    for (int ds = 0; ds < 8; ds++)
#pragma unroll
      for (int r = 0; r < 4; r++) accO[ds][r] *= alpha;
    // P (S^T C/D layout) -> Pl[q][key] (b64 packed), per-wave
#pragma unroll
    for (int n = 0; n < 4; n++) {
      alignas(8) unsigned short pk[4];
#pragma unroll
      for (int r = 0; r < 4; r++) pk[r] = f2bf(accS[n][r]);
      *(ushort4*)(pl + fr * 72 + n * 16 + fq * 4) = *(ushort4*)pk;
    }
#pragma unroll
    for (int ks2 = 0; ks2 < 2; ks2++) {
      const bf16x8 bp = *(const bf16x8*)(pl + fr * 72 + ks2 * 32 + fq * 8);
#pragma unroll
      for (int ds = 0; ds < 8; ds++) {
        const bf16x8 av =
            *(const bf16x8*)(Vbase + (long)(ds * 16 + fr) * 2048 + kt * 64 + ks2 * 32);
        accO[ds] = __builtin_amdgcn_mfma_f32_16x16x32_bf16(av, bp, accO[ds], 0, 0, 0);
      }
    }
  }
  const float inv = 1.f / l_i;
  const long tok = tokbase + qbase + w * 16 + fr;
#pragma unroll
  for (int ds = 0; ds < 8; ds++) {
    alignas(8) unsigned short o[4];
#pragma unroll
    for (int r = 0; r < 4; r++) o[r] = f2bf(accO[ds][r] * inv);
    *(ushort4*)(Y + tok * 2048 + h * 128 + ds * 16 + fq * 4) = *(ushort4*)o;
  }
}

// out GEMM: C f32 [4096,2048] = Y bf16 [4096,2048] @ Wp^T (f32 staged)
__global__ __launch_bounds__(256) void gemm_out(
    const unsigned short* __restrict__ A, const float* __restrict__ B,
    float* __restrict__ C, int K) {
  __shared__ unsigned short As[128 * 32];
  __shared__ float Bs[128 * 32];
  const int tid = threadIdx.x;
  const int lane = tid & 63;
  const int w = tid >> 6;
  const int wr = w >> 1, wc = w & 1;
  const int fr = lane & 15, fq = lane >> 4;
  const long m0 = (long)blockIdx.y * 128;
  const long n0 = (long)blockIdx.x * 128;
  const int srA = lane >> 2, scA = (lane & 3) * 8;
  const int srB = lane >> 3, scB = (lane & 7) * 4;
  f32x4 acc[4][4] = {};
  for (int k0 = 0; k0 < K; k0 += 32) {
    __syncthreads();
#pragma unroll
    for (int i = 0; i < 2; i++) {
      const int r = (w * 2 + i) * 16 + srA;
      async16(A + (m0 + r) * (long)K + k0 + scA, &As[(w * 2 + i) * 512]);
    }
#pragma unroll
    for (int c = 0; c < 4; c++) {
      const int rb = (w * 4 + c) * 8 + srB;
      const int kk = scB ^ ((rb & 3) * 8);
      async16(B + (n0 + rb) * (long)K + k0 + kk, &Bs[(w * 4 + c) * 256]);
    }
    __syncthreads();
    bf16x8 a[4], b[4];
#pragma unroll
    for (int i = 0; i < 4; i++)
      a[i] = *(const bf16x8*)&As[(wr * 64 + i * 16 + fr) * 32 + fq * 8];
#pragma unroll
    for (int j = 0; j < 4; j++) {
      const int rr = wc * 64 + j * 16 + fr;
      const float* bp = &Bs[rr * 32 + ((fq * 8) ^ ((rr & 3) * 8))];
      const f32x4 lo = *(const f32x4*)bp;
      const f32x4 hi = *(const f32x4*)(bp + 4);
      union { bf16x8 v; unsigned short u[8]; } t;
      t.u[0] = f2bf(lo[0]); t.u[1] = f2bf(lo[1]);
      t.u[2] = f2bf(lo[2]); t.u[3] = f2bf(lo[3]);
      t.u[4] = f2bf(hi[0]); t.u[5] = f2bf(hi[1]);
      t.u[6] = f2bf(hi[2]); t.u[7] = f2bf(hi[3]);
      b[j] = t.v;
    }
#pragma unroll
    for (int i = 0; i < 4; i++)
#pragma unroll
      for (int j = 0; j < 4; j++)
        acc[i][j] =
            __builtin_amdgcn_mfma_f32_16x16x32_bf16(a[i], b[j], acc[i][j], 0, 0, 0);
  }
#pragma unroll
  for (int i = 0; i < 4; i++)
#pragma unroll
    for (int j = 0; j < 4; j++)
#pragma unroll
      for (int r = 0; r < 4; r++) {
        const long m = m0 + wr * 64 + i * 16 + fq * 4 + r;
        const long n = n0 + wc * 64 + j * 16 + fr;
        C[m * 2048 + n] = acc[i][j][r];
      }
}

extern "C" void kernel_launch(void* const* d_in, const int* in_sizes, int n_in,
                              void* d_out, int out_size, void* d_ws, size_t ws_size,
                              hipStream_t stream) {
  (void)out_size;
  (void)ws_size;
  const float *x = 0, *Wq = 0, *Wp = 0, *g = 0;
  for (int i = 0; i < n_in; i++) {
    switch (in_sizes[i]) {
      case 8388608: x = (const float*)d_in[i]; break;    // [2,2048,2048]
      case 12582912: Wq = (const float*)d_in[i]; break;  // [6144,2048]
      case 4194304: Wp = (const float*)d_in[i]; break;   // [2048,2048]
      case 2048: g = (const float*)d_in[i]; break;       // [2048]
    }
  }
  if (!x) x = (const float*)d_in[0];
  if (!Wq) Wq = (const float*)d_in[1];
  if (!Wp) Wp = (const float*)d_in[2];
  if (!g) g = (const float*)d_in[3];
  float* out = (float*)d_out;
  char* ws = (char*)d_ws;
  unsigned short* QK = (unsigned short*)ws;                 // 32 MiB [q|k] stride 4096
  unsigned short* VtG = (unsigned short*)(ws + (32l << 20));  // 16 MiB [b][h][128][2048]
  unsigned short* Y = (unsigned short*)(ws + (48l << 20));    // 16 MiB -> 64 total
  unsigned short* xb = Y;  // x-bf16 staged in Y region (dead until attn writes Y)

  cvt_bf16_k<<<4096, 256, 0, stream>>>(x, xb, 1048576);
  gemm_qkv<<<dim3(48, 32), 256, 0, stream>>>(xb, Wq, QK, VtG, 2048);
  rms_rope<<<4096, 256, 0, stream>>>(QK, g);
  attn<<<dim3(32, 32), 256, 0, stream>>>(QK, VtG, Y);
  gemm_out<<<dim3(16, 32), 256, 0, stream>>>(Y, Wp, out, 2048);
}